// Round 4
// baseline (739.143 us; speedup 1.0000x reference)
//
#include <hip/hip_runtime.h>
#include <hip/hip_bf16.h>
#include <stdint.h>

// ---------------------------------------------------------------------------
// MoE dense:  B=4 T=2048 D=1024 H=2048 E=8   (fp32 in/out, bf16 MFMA compute)
// R10: crack read/MFMA serialization (R9 wall = LDS+MFMA SUM, not max):
//   - per K-tile body re-ordered into 2 k-half streams, dependency-local:
//     {4 B-frag reads; 8x(1 A-frag read -> 4 MFMA)} so lgkm ladders overlap
//     LDS service under the MFMA stream; frag liveness ~6 regs (kills gemm1
//     spill risk: R9 kept 24 frags live)
//   - T19 sched_group_barrier pins the interleave: per half
//     {DSR 4} + Nx{DSR 1, MFMA 4}; sched_barrier(0) fences scope the region
//   - setprio dropped from tile bodies (SOPP may split the sched region;
//     T5 ~0% on non-phase-split structures per m190)
//   - staging / T2 swizzle (conflicts=0) / XCD swizzle / 1 barrier per tile /
//     vmcnt(0)-with-full-tile-lead / epilogues unchanged (proven R9)
// ws layout: gate@0 (1MB), xb@1 (16), W1t@17 (4G), W2t@17+4G (4G),
//            hg@17+8G (32G).  need = 17 + 40G MB.
// ---------------------------------------------------------------------------

typedef __bf16 bf16_t;
typedef bf16_t bf16x8 __attribute__((ext_vector_type(8)));
typedef bf16_t bf16x4 __attribute__((ext_vector_type(4)));
typedef float  f32x4  __attribute__((ext_vector_type(4)));

#define Ddim 1024
#define Hdim 2048
#define Edim 8
#define Mdim 8192

__device__ __forceinline__ void async16(const void* g, const void* l) {
  __builtin_amdgcn_global_load_lds(
      (const __attribute__((address_space(1))) void*)(uintptr_t)g,
      (__attribute__((address_space(3))) void*)(uint32_t)(uintptr_t)l,
      16, 0, 0);
}

#define MFMA(a, b, c) __builtin_amdgcn_mfma_f32_16x16x32_bf16((a), (b), (c), 0, 0, 0)

#define WAIT_VM0() do {                                    \
    asm volatile("s_waitcnt vmcnt(0)" ::: "memory");       \
    __builtin_amdgcn_sched_barrier(0);                     \
  } while (0)

// sched_group_barrier masks (LLVM SchedGroupMask): MFMA=0x8, DS_READ=0x100
#define SGB(mask, n) __builtin_amdgcn_sched_group_barrier((mask), (n), 0)

// ---------------- gating: one wave per token (verified R4/R5) -------------
__global__ void gating_kernel(const float* __restrict__ x,
                              const float* __restrict__ Wg,
                              const float* __restrict__ bg,
                              float* __restrict__ gate) {
  const int lane = threadIdx.x & 63;
  const int wid  = threadIdx.x >> 6;
  const int t    = blockIdx.x * 4 + wid;
  const float* xr = x + (size_t)t * Ddim;
  float acc[8] = {0.f,0.f,0.f,0.f,0.f,0.f,0.f,0.f};
  for (int i = lane; i < Ddim; i += 64) {
    float xv = xr[i];
    f32x4 a = *(const f32x4*)(Wg + (size_t)i * 8);
    f32x4 b = *(const f32x4*)(Wg + (size_t)i * 8 + 4);
    acc[0] += xv * a[0]; acc[1] += xv * a[1];
    acc[2] += xv * a[2]; acc[3] += xv * a[3];
    acc[4] += xv * b[0]; acc[5] += xv * b[1];
    acc[6] += xv * b[2]; acc[7] += xv * b[3];
  }
  #pragma unroll
  for (int e = 0; e < 8; ++e) {
    #pragma unroll
    for (int off = 32; off; off >>= 1)
      acc[e] += __shfl_xor(acc[e], off, 64);
  }
  if (lane == 0) {
    float l[8], mx = -1e30f;
    #pragma unroll
    for (int e = 0; e < 8; ++e) { l[e] = acc[e] + bg[e]; mx = fmaxf(mx, l[e]); }
    float s = 0.f;
    #pragma unroll
    for (int e = 0; e < 8; ++e) { l[e] = __expf(l[e] - mx); s += l[e]; }
    float inv = 1.f / s;
    #pragma unroll
    for (int e = 0; e < 8; ++e) gate[(size_t)t * 8 + e] = l[e] * inv;
  }
}

// ---------------- x fp32 -> bf16 ------------------------------------------
__global__ void cvt_x(const float* __restrict__ a, bf16_t* __restrict__ o) {
  const size_t i = ((size_t)blockIdx.x * 256 + threadIdx.x) * 8;
  f32x4 v0 = *(const f32x4*)(a + i);
  f32x4 v1 = *(const f32x4*)(a + i + 4);
  bf16x8 b;
  b[0]=(bf16_t)v0[0]; b[1]=(bf16_t)v0[1]; b[2]=(bf16_t)v0[2]; b[3]=(bf16_t)v0[3];
  b[4]=(bf16_t)v1[0]; b[5]=(bf16_t)v1[1]; b[6]=(bf16_t)v1[2]; b[7]=(bf16_t)v1[3];
  *(bf16x8*)(o + i) = b;
}

// ------- batched transpose [R,C] fp32 -> [C,R] bf16, z = expert-in-group --
__global__ void transpose_f32_bf16(const float* __restrict__ src,
                                   bf16_t* __restrict__ dst, int R, int C) {
  __shared__ bf16_t tile[32][33];
  const size_t zo = (size_t)blockIdx.z * (size_t)R * C;
  src += zo; dst += zo;
  const int r0 = blockIdx.y * 32, c0 = blockIdx.x * 32;
  const int tr = threadIdx.x >> 3;
  const int tc = (threadIdx.x & 7) * 4;
  f32x4 v = *(const f32x4*)(src + (size_t)(r0 + tr) * C + c0 + tc);
  tile[tr][tc+0] = (bf16_t)v[0]; tile[tr][tc+1] = (bf16_t)v[1];
  tile[tr][tc+2] = (bf16_t)v[2]; tile[tr][tc+3] = (bf16_t)v[3];
  __syncthreads();
  bf16x4 o;
  o[0] = tile[tc+0][tr]; o[1] = tile[tc+1][tr];
  o[2] = tile[tc+2][tr]; o[3] = tile[tc+3][tr];
  *(bf16x4*)(dst + (size_t)(c0 + tr) * R + r0 + tc) = o;
}

// ---------------- GEMM1: hg[z] = gate_e * relu(xb @ W1t[z]^T + b1[e]) -----
// BM=256 BN=256 BK=64, 512 thr / 8 waves (2Mx4N, wave-tile 128x64).
// Per K-tile: stage 8; two k-half streams {4 B-reads; 8x(A-read, 4 MFMA)}
// pinned by SGB; vmcnt(0) (full-tile lead); 1 raw barrier.
// grid (Hdim/256, Mdim/256, G); K = Ddim.
__launch_bounds__(512, 2)
__global__ void gemm1_kernel(const bf16_t* __restrict__ A,        // xb [M,D]
                             const bf16_t* __restrict__ W1tAll,   // [G,H,D]
                             const float*  __restrict__ gate,
                             const float*  __restrict__ b1,       // [E,H]
                             bf16_t* __restrict__ hgAll,          // [G,M,H]
                             int e0) {
  __shared__ alignas(16) bf16_t sA[2][256 * 64];   // 2 x 32KB
  __shared__ alignas(16) bf16_t sB[2][256 * 64];   // 2 x 32KB   (128KB total)

  const int tid  = threadIdx.x;
  const int lane = tid & 63;
  const int wid  = tid >> 6;
  const int wm   = wid >> 2, wn = wid & 3;     // 2M x 4N waves
  const int lrow = lane & 15, quad = lane >> 4;
  const int sb   = quad ^ (lrow & 7);          // swizzled 16B slot base

  const int z = blockIdx.z;
  const int e = e0 + z;
  const bf16_t* Bt = W1tAll + (size_t)z * Hdim * Ddim;
  bf16_t* hg = hgAll + (size_t)z * (size_t)Mdim * Hdim;
  const float* bias = b1 + (size_t)e * Hdim;

  // XCD swizzle within z-plane: 256 wgs -> 8 XCDs x 32
  const int bid = blockIdx.y * 8 + blockIdx.x;
  const int xcd = bid & 7, loc = bid >> 3;
  const int tileM = (xcd * 4 + (loc >> 3)) * 256;
  const int tileN = (loc & 7) * 256;

  // staging: thread -> (row = tid>>3, swizzled col16 = (tid&7) ^ (row&7))
  const int trow = tid >> 3;
  const int tsw  = ((tid & 7) ^ (trow & 7)) << 4;
  const int ldst = tid << 4;
  const size_t SA = (size_t)64 * Ddim * 2;     // 64-row byte stride

  const char* a0 = (const char*)(A  + (size_t)(tileM + trow) * Ddim) + tsw;
  const char* b0 = (const char*)(Bt + (size_t)(tileN + trow) * Ddim) + tsw;
  char* curA = (char*)&sA[0][0]; char* nxtA = (char*)&sA[1][0];
  char* curB = (char*)&sB[0][0]; char* nxtB = (char*)&sB[1][0];

  // prologue: fully stage K-tile 0, drain, publish
  async16(a0,          curA + 0 * 8192 + ldst);
  async16(a0 + SA,     curA + 1 * 8192 + ldst);
  async16(a0 + 2 * SA, curA + 2 * 8192 + ldst);
  async16(a0 + 3 * SA, curA + 3 * 8192 + ldst);
  async16(b0,          curB + 0 * 8192 + ldst);
  async16(b0 + SA,     curB + 1 * 8192 + ldst);
  async16(b0 + 2 * SA, curB + 2 * 8192 + ldst);
  async16(b0 + 3 * SA, curB + 3 * 8192 + ldst);
  a0 += 128; b0 += 128;
  WAIT_VM0();
  __builtin_amdgcn_s_barrier();

  f32x4 acc[8][4] = {};
  const int offA0 = (wm * 128 + lrow) * 128 + sb * 16;
  const int offA1 = (wm * 128 + lrow) * 128 + (sb ^ 4) * 16;
  const int offB0 = (wn * 64  + lrow) * 128 + sb * 16;
  const int offB1 = (wn * 64  + lrow) * 128 + (sb ^ 4) * 16;

  #pragma unroll 1
  for (int kk = 0; kk < Ddim / 64; ++kk) {
    const bool notlast = (kk + 1 < Ddim / 64);
    __builtin_amdgcn_sched_barrier(0);
    // stage K-tile kk+1 (issued at tile top -> full-tile lead on the drain)
    if (notlast) {
      async16(a0,          nxtA + 0 * 8192 + ldst);
      async16(a0 + SA,     nxtA + 1 * 8192 + ldst);
      async16(a0 + 2 * SA, nxtA + 2 * 8192 + ldst);
      async16(a0 + 3 * SA, nxtA + 3 * 8192 + ldst);
      async16(b0,          nxtB + 0 * 8192 + ldst);
      async16(b0 + SA,     nxtB + 1 * 8192 + ldst);
      async16(b0 + 2 * SA, nxtB + 2 * 8192 + ldst);
      async16(b0 + 3 * SA, nxtB + 3 * 8192 + ldst);
    }
    __builtin_amdgcn_sched_barrier(0);

    // two k-half streams, dependency-local order
    #pragma unroll
    for (int h = 0; h < 2; ++h) {
      const int oA = h ? offA1 : offA0;
      const int oB = h ? offB1 : offB0;
      bf16x8 bfr[4];
      #pragma unroll
      for (int j = 0; j < 4; ++j)
        bfr[j] = *(const bf16x8*)(curB + oB + j * 2048);
      #pragma unroll
      for (int i = 0; i < 8; ++i) {
        bf16x8 af = *(const bf16x8*)(curA + oA + i * 2048);
        #pragma unroll
        for (int j = 0; j < 4; ++j)
          acc[i][j] = MFMA(af, bfr[j], acc[i][j]);
      }
    }
    // pin the interleave: per half {DSR 4} + 8x{DSR 1, MFMA 4}
    #pragma unroll
    for (int h = 0; h < 2; ++h) {
      SGB(0x100, 4);
      #pragma unroll
      for (int r = 0; r < 8; ++r) { SGB(0x100, 1); SGB(0x8, 4); }
    }
    __builtin_amdgcn_sched_barrier(0);

    WAIT_VM0();                          // loads had a full tile in flight
    __builtin_amdgcn_s_barrier();        // publish K-tile kk+1
    a0 += 128; b0 += 128;
    char* t;
    t = curA; curA = nxtA; nxtA = t;
    t = curB; curB = nxtB; nxtB = t;
  }

  // epilogue: bias + relu + gate, write bf16
  const int col0 = tileN + wn * 64 + lrow;
  float bcol[4];
  #pragma unroll
  for (int j = 0; j < 4; ++j) bcol[j] = bias[col0 + j * 16];
  #pragma unroll
  for (int i = 0; i < 8; ++i) {
    #pragma unroll
    for (int r = 0; r < 4; ++r) {
      const int row = tileM + wm * 128 + i * 16 + quad * 4 + r;
      const float g = gate[(size_t)row * 8 + e];
      #pragma unroll
      for (int j = 0; j < 4; ++j) {
        float v = acc[i][j][r] + bcol[j];
        v = fmaxf(v, 0.f) * g;
        hg[(size_t)row * Hdim + col0 + j * 16] = (bf16_t)v;
      }
    }
  }
}

// ---------------- GEMM2: out (+)= sum_g hg[g] @ W2t[g]^T + gate*b2 --------
// BM=256 BN=128 BK=64, 512 thr / 8 waves 4Mx2N (wave-tile 64x64).
// Per K-tile: stage 6; two k-half streams {4 B-reads; 4x(A-read, 4 MFMA)}
// pinned by SGB.  K fused over group (NKT = G*32).
// grid (Ddim/128, Mdim/256) = 256.
template <int G, bool FIRST>
__launch_bounds__(512, 2)
__global__ void gemm2_kernel(const bf16_t* __restrict__ hgAll,    // [G,M,H]
                             const bf16_t* __restrict__ W2tAll,   // [G,D,H]
                             const float*  __restrict__ gate,
                             const float*  __restrict__ b2,       // [E,D]
                             float* __restrict__ out,             // [M,D]
                             int e0) {
  __shared__ alignas(16) bf16_t sA[2][256 * 64];   // 2 x 32KB
  __shared__ alignas(16) bf16_t sB[2][128 * 64];   // 2 x 16KB  (96KB total)

  const int tid  = threadIdx.x;
  const int lane = tid & 63;
  const int wid  = tid >> 6;
  const int wm   = wid >> 1, wn = wid & 1;     // 4M x 2N waves
  const int lrow = lane & 15, quad = lane >> 4;
  const int sb   = quad ^ (lrow & 7);

  const int bid = blockIdx.y * 8 + blockIdx.x;
  const int xcd = bid & 7, loc = bid >> 3;
  const int tileM = (xcd * 4 + (loc >> 3)) * 256;
  const int tileN = (loc & 7) * 128;

  const int trow = tid >> 3;
  const int tsw  = ((tid & 7) ^ (trow & 7)) << 4;
  const int ldst = tid << 4;
  const size_t S = (size_t)64 * Hdim * 2;          // 64-row byte stride

  const char* a0 = (const char*)(hgAll  + (size_t)(tileM + trow) * Hdim) + tsw;
  const char* b0 = (const char*)(W2tAll + (size_t)(tileN + trow) * Hdim) + tsw;
  char* curA = (char*)&sA[0][0]; char* nxtA = (char*)&sA[1][0];
  char* curB = (char*)&sB[0][0]; char* nxtB = (char*)&sB[1][0];

  // prologue: stage K-tile 0, drain, publish
  async16(a0,         curA + 0 * 8192 + ldst);
  async16(a0 + S,     curA + 1 * 8192 + ldst);
  async16(a0 + 2 * S, curA + 2 * 8192 + ldst);
  async16(a0 + 3 * S, curA + 3 * 8192 + ldst);
  async16(b0,         curB + 0 * 8192 + ldst);
  async16(b0 + S,     curB + 1 * 8192 + ldst);
  a0 += 128; b0 += 128;
  WAIT_VM0();
  __builtin_amdgcn_s_barrier();

  f32x4 acc[4][4] = {};
  const int offA0 = (wm * 64 + lrow) * 128 + sb * 16;
  const int offA1 = (wm * 64 + lrow) * 128 + (sb ^ 4) * 16;
  const int offB0 = (wn * 64 + lrow) * 128 + sb * 16;
  const int offB1 = (wn * 64 + lrow) * 128 + (sb ^ 4) * 16;

  const int NKT = G * (Hdim / 64);
  #pragma unroll 1
  for (int kk = 0; kk < NKT; ++kk) {
    const bool notlast = (kk + 1 < NKT);
    __builtin_amdgcn_sched_barrier(0);
    // expert-boundary rebase of staging pointers (targets kk+1)
    if (notlast && (((kk + 1) & 31) == 0)) {
      const int gn = (kk + 1) >> 5;
      a0 = (const char*)(hgAll  + (size_t)gn * Mdim * Hdim
                         + (size_t)(tileM + trow) * Hdim) + tsw;
      b0 = (const char*)(W2tAll + (size_t)gn * Ddim * Hdim
                         + (size_t)(tileN + trow) * Hdim) + tsw;
    }
    if (notlast) {
      async16(a0,         nxtA + 0 * 8192 + ldst);
      async16(a0 + S,     nxtA + 1 * 8192 + ldst);
      async16(a0 + 2 * S, nxtA + 2 * 8192 + ldst);
      async16(a0 + 3 * S, nxtA + 3 * 8192 + ldst);
      async16(b0,         nxtB + 0 * 8192 + ldst);
      async16(b0 + S,     nxtB + 1 * 8192 + ldst);
    }
    __builtin_amdgcn_sched_barrier(0);

    #pragma unroll
    for (int h = 0; h < 2; ++h) {
      const int oA = h ? offA1 : offA0;
      const int oB = h ? offB1 : offB0;
      bf16x8 bfr[4];
      #pragma unroll
      for (int j = 0; j < 4; ++j)
        bfr[j] = *(const bf16x8*)(curB + oB + j * 2048);
      #pragma unroll
      for (int i = 0; i < 4; ++i) {
        bf16x8 af = *(const bf16x8*)(curA + oA + i * 2048);
        #pragma unroll
        for (int j = 0; j < 4; ++j)
          acc[i][j] = MFMA(af, bfr[j], acc[i][j]);
      }
    }
    // pin the interleave: per half {DSR 4} + 4x{DSR 1, MFMA 4}
    #pragma unroll
    for (int h = 0; h < 2; ++h) {
      SGB(0x100, 4);
      #pragma unroll
      for (int r = 0; r < 4; ++r) { SGB(0x100, 1); SGB(0x8, 4); }
    }
    __builtin_amdgcn_sched_barrier(0);

    WAIT_VM0();
    __builtin_amdgcn_s_barrier();
    a0 += 128; b0 += 128;
    char* t;
    t = curA; curA = nxtA; nxtA = t;
    t = curB; curB = nxtB; nxtB = t;
  }

  // epilogue: add sum_g gate[row,e0+g]*b2[e0+g,col]
  const int col0 = tileN + wn * 64 + lrow;
  float b2c[4][G];
  #pragma unroll
  for (int j = 0; j < 4; ++j)
    #pragma unroll
    for (int g = 0; g < G; ++g)
      b2c[j][g] = b2[(size_t)(e0 + g) * Ddim + col0 + j * 16];

  #pragma unroll
  for (int i = 0; i < 4; ++i) {
    #pragma unroll
    for (int r = 0; r < 4; ++r) {
      const int row = tileM + wm * 64 + i * 16 + quad * 4 + r;
      const float* gr = gate + (size_t)row * 8 + e0;
      float gv[G];
      #pragma unroll
      for (int g = 0; g < G; ++g) gv[g] = gr[g];
      #pragma unroll
      for (int j = 0; j < 4; ++j) {
        float v = acc[i][j][r];
        #pragma unroll
        for (int g = 0; g < G; ++g) v += gv[g] * b2c[j][g];
        if (FIRST) out[(size_t)row * Ddim + col0 + j * 16] = v;
        else       out[(size_t)row * Ddim + col0 + j * 16] += v;
      }
    }
  }
}

extern "C" void kernel_launch(void* const* d_in, const int* in_sizes, int n_in,
                              void* d_out, int out_size, void* d_ws, size_t ws_size,
                              hipStream_t stream) {
  const float* x  = (const float*)d_in[0];
  const float* Wg = (const float*)d_in[1];
  const float* bg = (const float*)d_in[2];
  const float* W1 = (const float*)d_in[3];
  const float* b1 = (const float*)d_in[4];
  const float* W2 = (const float*)d_in[5];
  const float* b2 = (const float*)d_in[6];
  float* out = (float*)d_out;

  // ws-adaptive group size: need = 17 + 40G MB
  int G = 1;
  if      (ws_size >= (size_t)(17 + 40 * 8) << 20) G = 8;
  else if (ws_size >= (size_t)(17 + 40 * 4) << 20) G = 4;
  else if (ws_size >= (size_t)(17 + 40 * 2) << 20) G = 2;

  char* ws = (char*)d_ws;
  float*  gate = (float*)ws;                                     // 1 MB region
  bf16_t* xb   = (bf16_t*)(ws + (1u << 20));                     // 16 MB
  bf16_t* W1t  = (bf16_t*)(ws + (17u << 20));                    // 4G MB
  bf16_t* W2t  = (bf16_t*)(ws + ((size_t)(17 + 4 * G) << 20));   // 4G MB
  bf16_t* hg   = (bf16_t*)(ws + ((size_t)(17 + 8 * G) << 20));   // 32G MB

  gating_kernel<<<Mdim / 4, 256, 0, stream>>>(x, Wg, bg, gate);
  cvt_x<<<(Mdim * Ddim) / (256 * 8), 256, 0, stream>>>(x, xb);

  const int nGroups = Edim / G;
  for (int gi = 0; gi < nGroups; ++gi) {
    const int e0 = gi * G;
    transpose_f32_bf16<<<dim3(Hdim / 32, Ddim / 32, G), 256, 0, stream>>>(
        W1 + (size_t)e0 * Ddim * Hdim, W1t, Ddim, Hdim);
    transpose_f32_bf16<<<dim3(Ddim / 32, Hdim / 32, G), 256, 0, stream>>>(
        W2 + (size_t)e0 * Hdim * Ddim, W2t, Hdim, Ddim);

    gemm1_kernel<<<dim3(Hdim / 256, Mdim / 256, G), 512, 0, stream>>>(
        xb, W1t, gate, b1, hg, e0);

    const dim3 g2(Ddim / 128, Mdim / 256);
    const bool first = (gi == 0);
    if (G == 8)      gemm2_kernel<8, true ><<<g2, 512, 0, stream>>>(hg, W2t, gate, b2, out, e0);
    else if (G == 4) {
      if (first)     gemm2_kernel<4, true ><<<g2, 512, 0, stream>>>(hg, W2t, gate, b2, out, e0);
      else           gemm2_kernel<4, false><<<g2, 512, 0, stream>>>(hg, W2t, gate, b2, out, e0);
    } else if (G == 2) {
      if (first)     gemm2_kernel<2, true ><<<g2, 512, 0, stream>>>(hg, W2t, gate, b2, out, e0);
      else           gemm2_kernel<2, false><<<g2, 512, 0, stream>>>(hg, W2t, gate, b2, out, e0);
    } else {
      if (first)     gemm2_kernel<1, true ><<<g2, 512, 0, stream>>>(hg, W2t, gate, b2, out, e0);
      else           gemm2_kernel<1, false><<<g2, 512, 0, stream>>>(hg, W2t, gate, b2, out, e0);
    }
  }
}

// Round 5
// 704.996 us; speedup vs baseline: 1.0484x; 1.0484x over previous
//
#include <hip/hip_runtime.h>
#include <hip/hip_bf16.h>
#include <stdint.h>

// ---------------------------------------------------------------------------
// MoE dense:  B=4 T=2048 D=1024 H=2048 E=8   (fp32 in/out, bf16 MFMA compute)
// R11: attribution-clean split after R10's SGB regression (gemm2 143->156):
//   - gemm2: EXACT R9 body restored (bulk frag reads, compiler-laddered lgkm,
//     setprio around MFMA cluster, vmcnt(0)-full-lead, 1 barrier/tile). 143us.
//   - gemm1: R9 structure, loop body ONLY changed to dependency-local
//     half-streams {4 B-reads; 8x(1 A-read -> 4 MFMA)} WITHOUT SGB.
//     Rationale: R9 gemm1 held 24 live frags (96 VGPR) + 128 acc -> spill
//     boundary; dep-local cuts frag liveness to ~20 regs. R10 indirect
//     evidence: total +18us while gemm2 alone +26us => gemm1 improved.
// ws layout: gate@0 (1MB), xb@1 (16), W1t@17 (4G), W2t@17+4G (4G),
//            hg@17+8G (32G).  need = 17 + 40G MB.
// ---------------------------------------------------------------------------

typedef __bf16 bf16_t;
typedef bf16_t bf16x8 __attribute__((ext_vector_type(8)));
typedef bf16_t bf16x4 __attribute__((ext_vector_type(4)));
typedef float  f32x4  __attribute__((ext_vector_type(4)));

#define Ddim 1024
#define Hdim 2048
#define Edim 8
#define Mdim 8192

__device__ __forceinline__ void async16(const void* g, const void* l) {
  __builtin_amdgcn_global_load_lds(
      (const __attribute__((address_space(1))) void*)(uintptr_t)g,
      (__attribute__((address_space(3))) void*)(uint32_t)(uintptr_t)l,
      16, 0, 0);
}

#define MFMA(a, b, c) __builtin_amdgcn_mfma_f32_16x16x32_bf16((a), (b), (c), 0, 0, 0)

#define WAIT_VM0() do {                                    \
    asm volatile("s_waitcnt vmcnt(0)" ::: "memory");       \
    __builtin_amdgcn_sched_barrier(0);                     \
  } while (0)

// ---------------- gating: one wave per token (verified R4/R5) -------------
__global__ void gating_kernel(const float* __restrict__ x,
                              const float* __restrict__ Wg,
                              const float* __restrict__ bg,
                              float* __restrict__ gate) {
  const int lane = threadIdx.x & 63;
  const int wid  = threadIdx.x >> 6;
  const int t    = blockIdx.x * 4 + wid;
  const float* xr = x + (size_t)t * Ddim;
  float acc[8] = {0.f,0.f,0.f,0.f,0.f,0.f,0.f,0.f};
  for (int i = lane; i < Ddim; i += 64) {
    float xv = xr[i];
    f32x4 a = *(const f32x4*)(Wg + (size_t)i * 8);
    f32x4 b = *(const f32x4*)(Wg + (size_t)i * 8 + 4);
    acc[0] += xv * a[0]; acc[1] += xv * a[1];
    acc[2] += xv * a[2]; acc[3] += xv * a[3];
    acc[4] += xv * b[0]; acc[5] += xv * b[1];
    acc[6] += xv * b[2]; acc[7] += xv * b[3];
  }
  #pragma unroll
  for (int e = 0; e < 8; ++e) {
    #pragma unroll
    for (int off = 32; off; off >>= 1)
      acc[e] += __shfl_xor(acc[e], off, 64);
  }
  if (lane == 0) {
    float l[8], mx = -1e30f;
    #pragma unroll
    for (int e = 0; e < 8; ++e) { l[e] = acc[e] + bg[e]; mx = fmaxf(mx, l[e]); }
    float s = 0.f;
    #pragma unroll
    for (int e = 0; e < 8; ++e) { l[e] = __expf(l[e] - mx); s += l[e]; }
    float inv = 1.f / s;
    #pragma unroll
    for (int e = 0; e < 8; ++e) gate[(size_t)t * 8 + e] = l[e] * inv;
  }
}

// ---------------- x fp32 -> bf16 ------------------------------------------
__global__ void cvt_x(const float* __restrict__ a, bf16_t* __restrict__ o) {
  const size_t i = ((size_t)blockIdx.x * 256 + threadIdx.x) * 8;
  f32x4 v0 = *(const f32x4*)(a + i);
  f32x4 v1 = *(const f32x4*)(a + i + 4);
  bf16x8 b;
  b[0]=(bf16_t)v0[0]; b[1]=(bf16_t)v0[1]; b[2]=(bf16_t)v0[2]; b[3]=(bf16_t)v0[3];
  b[4]=(bf16_t)v1[0]; b[5]=(bf16_t)v1[1]; b[6]=(bf16_t)v1[2]; b[7]=(bf16_t)v1[3];
  *(bf16x8*)(o + i) = b;
}

// ------- batched transpose [R,C] fp32 -> [C,R] bf16, z = expert-in-group --
__global__ void transpose_f32_bf16(const float* __restrict__ src,
                                   bf16_t* __restrict__ dst, int R, int C) {
  __shared__ bf16_t tile[32][33];
  const size_t zo = (size_t)blockIdx.z * (size_t)R * C;
  src += zo; dst += zo;
  const int r0 = blockIdx.y * 32, c0 = blockIdx.x * 32;
  const int tr = threadIdx.x >> 3;
  const int tc = (threadIdx.x & 7) * 4;
  f32x4 v = *(const f32x4*)(src + (size_t)(r0 + tr) * C + c0 + tc);
  tile[tr][tc+0] = (bf16_t)v[0]; tile[tr][tc+1] = (bf16_t)v[1];
  tile[tr][tc+2] = (bf16_t)v[2]; tile[tr][tc+3] = (bf16_t)v[3];
  __syncthreads();
  bf16x4 o;
  o[0] = tile[tc+0][tr]; o[1] = tile[tc+1][tr];
  o[2] = tile[tc+2][tr]; o[3] = tile[tc+3][tr];
  *(bf16x4*)(dst + (size_t)(c0 + tr) * R + r0 + tc) = o;
}

// ---------------- GEMM1: hg[z] = gate_e * relu(xb @ W1t[z]^T + b1[e]) -----
// BM=256 BN=256 BK=64, 512 thr / 8 waves (2Mx4N, wave-tile 128x64).
// Per K-tile: stage 8; dependency-local half-streams
// {4 B-reads; 8x(1 A-read -> 4 MFMA)} (no SGB); vmcnt(0) full-lead;
// 1 raw barrier.  grid (Hdim/256, Mdim/256, G); K = Ddim.
__launch_bounds__(512, 2)
__global__ void gemm1_kernel(const bf16_t* __restrict__ A,        // xb [M,D]
                             const bf16_t* __restrict__ W1tAll,   // [G,H,D]
                             const float*  __restrict__ gate,
                             const float*  __restrict__ b1,       // [E,H]
                             bf16_t* __restrict__ hgAll,          // [G,M,H]
                             int e0) {
  __shared__ alignas(16) bf16_t sA[2][256 * 64];   // 2 x 32KB
  __shared__ alignas(16) bf16_t sB[2][256 * 64];   // 2 x 32KB   (128KB total)

  const int tid  = threadIdx.x;
  const int lane = tid & 63;
  const int wid  = tid >> 6;
  const int wm   = wid >> 2, wn = wid & 3;     // 2M x 4N waves
  const int lrow = lane & 15, quad = lane >> 4;
  const int sb   = quad ^ (lrow & 7);          // swizzled 16B slot base

  const int z = blockIdx.z;
  const int e = e0 + z;
  const bf16_t* Bt = W1tAll + (size_t)z * Hdim * Ddim;
  bf16_t* hg = hgAll + (size_t)z * (size_t)Mdim * Hdim;
  const float* bias = b1 + (size_t)e * Hdim;

  // XCD swizzle within z-plane: 256 wgs -> 8 XCDs x 32
  const int bid = blockIdx.y * 8 + blockIdx.x;
  const int xcd = bid & 7, loc = bid >> 3;
  const int tileM = (xcd * 4 + (loc >> 3)) * 256;
  const int tileN = (loc & 7) * 256;

  // staging: thread -> (row = tid>>3, swizzled col16 = (tid&7) ^ (row&7))
  const int trow = tid >> 3;
  const int tsw  = ((tid & 7) ^ (trow & 7)) << 4;
  const int ldst = tid << 4;
  const size_t SA = (size_t)64 * Ddim * 2;     // 64-row byte stride

  const char* a0 = (const char*)(A  + (size_t)(tileM + trow) * Ddim) + tsw;
  const char* b0 = (const char*)(Bt + (size_t)(tileN + trow) * Ddim) + tsw;
  char* curA = (char*)&sA[0][0]; char* nxtA = (char*)&sA[1][0];
  char* curB = (char*)&sB[0][0]; char* nxtB = (char*)&sB[1][0];

  // prologue: fully stage K-tile 0, drain, publish
  async16(a0,          curA + 0 * 8192 + ldst);
  async16(a0 + SA,     curA + 1 * 8192 + ldst);
  async16(a0 + 2 * SA, curA + 2 * 8192 + ldst);
  async16(a0 + 3 * SA, curA + 3 * 8192 + ldst);
  async16(b0,          curB + 0 * 8192 + ldst);
  async16(b0 + SA,     curB + 1 * 8192 + ldst);
  async16(b0 + 2 * SA, curB + 2 * 8192 + ldst);
  async16(b0 + 3 * SA, curB + 3 * 8192 + ldst);
  a0 += 128; b0 += 128;
  WAIT_VM0();
  __builtin_amdgcn_s_barrier();

  f32x4 acc[8][4] = {};
  const int offA0 = (wm * 128 + lrow) * 128 + sb * 16;
  const int offA1 = (wm * 128 + lrow) * 128 + (sb ^ 4) * 16;
  const int offB0 = (wn * 64  + lrow) * 128 + sb * 16;
  const int offB1 = (wn * 64  + lrow) * 128 + (sb ^ 4) * 16;

  #pragma unroll 1
  for (int kk = 0; kk < Ddim / 64; ++kk) {
    const bool notlast = (kk + 1 < Ddim / 64);
    __builtin_amdgcn_sched_barrier(0);
    // stage K-tile kk+1 (issued at tile top -> full-tile lead on the drain)
    if (notlast) {
      async16(a0,          nxtA + 0 * 8192 + ldst);
      async16(a0 + SA,     nxtA + 1 * 8192 + ldst);
      async16(a0 + 2 * SA, nxtA + 2 * 8192 + ldst);
      async16(a0 + 3 * SA, nxtA + 3 * 8192 + ldst);
      async16(b0,          nxtB + 0 * 8192 + ldst);
      async16(b0 + SA,     nxtB + 1 * 8192 + ldst);
      async16(b0 + 2 * SA, nxtB + 2 * 8192 + ldst);
      async16(b0 + 3 * SA, nxtB + 3 * 8192 + ldst);
    }
    __builtin_amdgcn_sched_barrier(0);

    // dependency-local half-streams: frag liveness ~5 regs + acc
    __builtin_amdgcn_s_setprio(1);
    #pragma unroll
    for (int h = 0; h < 2; ++h) {
      const int oA = h ? offA1 : offA0;
      const int oB = h ? offB1 : offB0;
      bf16x8 bfr[4];
      #pragma unroll
      for (int j = 0; j < 4; ++j)
        bfr[j] = *(const bf16x8*)(curB + oB + j * 2048);
      #pragma unroll
      for (int i = 0; i < 8; ++i) {
        bf16x8 af = *(const bf16x8*)(curA + oA + i * 2048);
        #pragma unroll
        for (int j = 0; j < 4; ++j)
          acc[i][j] = MFMA(af, bfr[j], acc[i][j]);
      }
    }
    __builtin_amdgcn_s_setprio(0);

    WAIT_VM0();                          // loads had a full tile in flight
    __builtin_amdgcn_s_barrier();        // publish K-tile kk+1
    a0 += 128; b0 += 128;
    char* t;
    t = curA; curA = nxtA; nxtA = t;
    t = curB; curB = nxtB; nxtB = t;
  }

  // epilogue: bias + relu + gate, write bf16
  const int col0 = tileN + wn * 64 + lrow;
  float bcol[4];
  #pragma unroll
  for (int j = 0; j < 4; ++j) bcol[j] = bias[col0 + j * 16];
  #pragma unroll
  for (int i = 0; i < 8; ++i) {
    #pragma unroll
    for (int r = 0; r < 4; ++r) {
      const int row = tileM + wm * 128 + i * 16 + quad * 4 + r;
      const float g = gate[(size_t)row * 8 + e];
      #pragma unroll
      for (int j = 0; j < 4; ++j) {
        float v = acc[i][j][r] + bcol[j];
        v = fmaxf(v, 0.f) * g;
        hg[(size_t)row * Hdim + col0 + j * 16] = (bf16_t)v;
      }
    }
  }
}

// ---------------- GEMM2: out (+)= sum_g hg[g] @ W2t[g]^T + gate*b2 --------
// EXACT R9 body.  BM=256 BN=128 BK=64, 512 thr / 8 waves 4Mx2N (wave-tile
// 64x64).  K fused over group (NKT = G*32).  grid (Ddim/128, Mdim/256)=256.
template <int G, bool FIRST>
__launch_bounds__(512, 2)
__global__ void gemm2_kernel(const bf16_t* __restrict__ hgAll,    // [G,M,H]
                             const bf16_t* __restrict__ W2tAll,   // [G,D,H]
                             const float*  __restrict__ gate,
                             const float*  __restrict__ b2,       // [E,D]
                             float* __restrict__ out,             // [M,D]
                             int e0) {
  __shared__ alignas(16) bf16_t sA[2][256 * 64];   // 2 x 32KB
  __shared__ alignas(16) bf16_t sB[2][128 * 64];   // 2 x 16KB  (96KB total)

  const int tid  = threadIdx.x;
  const int lane = tid & 63;
  const int wid  = tid >> 6;
  const int wm   = wid >> 1, wn = wid & 1;     // 4M x 2N waves
  const int lrow = lane & 15, quad = lane >> 4;
  const int sb   = quad ^ (lrow & 7);

  const int bid = blockIdx.y * 8 + blockIdx.x;
  const int xcd = bid & 7, loc = bid >> 3;
  const int tileM = (xcd * 4 + (loc >> 3)) * 256;
  const int tileN = (loc & 7) * 128;

  const int trow = tid >> 3;
  const int tsw  = ((tid & 7) ^ (trow & 7)) << 4;
  const int ldst = tid << 4;
  const size_t S = (size_t)64 * Hdim * 2;          // 64-row byte stride

  const char* a0 = (const char*)(hgAll  + (size_t)(tileM + trow) * Hdim) + tsw;
  const char* b0 = (const char*)(W2tAll + (size_t)(tileN + trow) * Hdim) + tsw;
  char* curA = (char*)&sA[0][0]; char* nxtA = (char*)&sA[1][0];
  char* curB = (char*)&sB[0][0]; char* nxtB = (char*)&sB[1][0];

  // prologue: stage K-tile 0, drain, publish
  async16(a0,         curA + 0 * 8192 + ldst);
  async16(a0 + S,     curA + 1 * 8192 + ldst);
  async16(a0 + 2 * S, curA + 2 * 8192 + ldst);
  async16(a0 + 3 * S, curA + 3 * 8192 + ldst);
  async16(b0,         curB + 0 * 8192 + ldst);
  async16(b0 + S,     curB + 1 * 8192 + ldst);
  a0 += 128; b0 += 128;
  WAIT_VM0();
  __builtin_amdgcn_s_barrier();

  f32x4 acc[4][4] = {};
  const int offA0 = (wm * 64 + lrow) * 128 + sb * 16;
  const int offA1 = (wm * 64 + lrow) * 128 + (sb ^ 4) * 16;
  const int offB0 = (wn * 64 + lrow) * 128 + sb * 16;
  const int offB1 = (wn * 64 + lrow) * 128 + (sb ^ 4) * 16;

  const int NKT = G * (Hdim / 64);
  #pragma unroll 1
  for (int kk = 0; kk < NKT; ++kk) {
    const bool notlast = (kk + 1 < NKT);
    __builtin_amdgcn_sched_barrier(0);
    // expert-boundary rebase of staging pointers (targets kk+1)
    if (notlast && (((kk + 1) & 31) == 0)) {
      const int gn = (kk + 1) >> 5;
      a0 = (const char*)(hgAll  + (size_t)gn * Mdim * Hdim
                         + (size_t)(tileM + trow) * Hdim) + tsw;
      b0 = (const char*)(W2tAll + (size_t)gn * Ddim * Hdim
                         + (size_t)(tileN + trow) * Hdim) + tsw;
    }
    if (notlast) {
      async16(a0,         nxtA + 0 * 8192 + ldst);
      async16(a0 + S,     nxtA + 1 * 8192 + ldst);
      async16(a0 + 2 * S, nxtA + 2 * 8192 + ldst);
      async16(a0 + 3 * S, nxtA + 3 * 8192 + ldst);
      async16(b0,         nxtB + 0 * 8192 + ldst);
      async16(b0 + S,     nxtB + 1 * 8192 + ldst);
    }
    bf16x8 afr[4][2], bfr[4][2];
    #pragma unroll
    for (int i = 0; i < 4; ++i) {
      afr[i][0] = *(const bf16x8*)(curA + offA0 + i * 2048);
      afr[i][1] = *(const bf16x8*)(curA + offA1 + i * 2048);
    }
    #pragma unroll
    for (int j = 0; j < 4; ++j) {
      bfr[j][0] = *(const bf16x8*)(curB + offB0 + j * 2048);
      bfr[j][1] = *(const bf16x8*)(curB + offB1 + j * 2048);
    }
    __builtin_amdgcn_s_setprio(1);
    #pragma unroll
    for (int i = 0; i < 4; ++i)
      #pragma unroll
      for (int j = 0; j < 4; ++j) {
        acc[i][j] = MFMA(afr[i][0], bfr[j][0], acc[i][j]);
        acc[i][j] = MFMA(afr[i][1], bfr[j][1], acc[i][j]);
      }
    __builtin_amdgcn_s_setprio(0);
    WAIT_VM0();
    __builtin_amdgcn_s_barrier();
    a0 += 128; b0 += 128;
    char* t;
    t = curA; curA = nxtA; nxtA = t;
    t = curB; curB = nxtB; nxtB = t;
  }

  // epilogue: add sum_g gate[row,e0+g]*b2[e0+g,col]
  const int col0 = tileN + wn * 64 + lrow;
  float b2c[4][G];
  #pragma unroll
  for (int j = 0; j < 4; ++j)
    #pragma unroll
    for (int g = 0; g < G; ++g)
      b2c[j][g] = b2[(size_t)(e0 + g) * Ddim + col0 + j * 16];

  #pragma unroll
  for (int i = 0; i < 4; ++i) {
    #pragma unroll
    for (int r = 0; r < 4; ++r) {
      const int row = tileM + wm * 64 + i * 16 + quad * 4 + r;
      const float* gr = gate + (size_t)row * 8 + e0;
      float gv[G];
      #pragma unroll
      for (int g = 0; g < G; ++g) gv[g] = gr[g];
      #pragma unroll
      for (int j = 0; j < 4; ++j) {
        float v = acc[i][j][r];
        #pragma unroll
        for (int g = 0; g < G; ++g) v += gv[g] * b2c[j][g];
        if (FIRST) out[(size_t)row * Ddim + col0 + j * 16] = v;
        else       out[(size_t)row * Ddim + col0 + j * 16] += v;
      }
    }
  }
}

extern "C" void kernel_launch(void* const* d_in, const int* in_sizes, int n_in,
                              void* d_out, int out_size, void* d_ws, size_t ws_size,
                              hipStream_t stream) {
  const float* x  = (const float*)d_in[0];
  const float* Wg = (const float*)d_in[1];
  const float* bg = (const float*)d_in[2];
  const float* W1 = (const float*)d_in[3];
  const float* b1 = (const float*)d_in[4];
  const float* W2 = (const float*)d_in[5];
  const float* b2 = (const float*)d_in[6];
  float* out = (float*)d_out;

  // ws-adaptive group size: need = 17 + 40G MB
  int G = 1;
  if      (ws_size >= (size_t)(17 + 40 * 8) << 20) G = 8;
  else if (ws_size >= (size_t)(17 + 40 * 4) << 20) G = 4;
  else if (ws_size >= (size_t)(17 + 40 * 2) << 20) G = 2;

  char* ws = (char*)d_ws;
  float*  gate = (float*)ws;                                     // 1 MB region
  bf16_t* xb   = (bf16_t*)(ws + (1u << 20));                     // 16 MB
  bf16_t* W1t  = (bf16_t*)(ws + (17u << 20));                    // 4G MB
  bf16_t* W2t  = (bf16_t*)(ws + ((size_t)(17 + 4 * G) << 20));   // 4G MB
  bf16_t* hg   = (bf16_t*)(ws + ((size_t)(17 + 8 * G) << 20));   // 32G MB

  gating_kernel<<<Mdim / 4, 256, 0, stream>>>(x, Wg, bg, gate);
  cvt_x<<<(Mdim * Ddim) / (256 * 8), 256, 0, stream>>>(x, xb);

  const int nGroups = Edim / G;
  for (int gi = 0; gi < nGroups; ++gi) {
    const int e0 = gi * G;
    transpose_f32_bf16<<<dim3(Hdim / 32, Ddim / 32, G), 256, 0, stream>>>(
        W1 + (size_t)e0 * Ddim * Hdim, W1t, Ddim, Hdim);
    transpose_f32_bf16<<<dim3(Ddim / 32, Hdim / 32, G), 256, 0, stream>>>(
        W2 + (size_t)e0 * Hdim * Ddim, W2t, Hdim, Ddim);

    gemm1_kernel<<<dim3(Hdim / 256, Mdim / 256, G), 512, 0, stream>>>(
        xb, W1t, gate, b1, hg, e0);

    const dim3 g2(Ddim / 128, Mdim / 256);
    const bool first = (gi == 0);
    if (G == 8)      gemm2_kernel<8, true ><<<g2, 512, 0, stream>>>(hg, W2t, gate, b2, out, e0);
    else if (G == 4) {
      if (first)     gemm2_kernel<4, true ><<<g2, 512, 0, stream>>>(hg, W2t, gate, b2, out, e0);
      else           gemm2_kernel<4, false><<<g2, 512, 0, stream>>>(hg, W2t, gate, b2, out, e0);
    } else if (G == 2) {
      if (first)     gemm2_kernel<2, true ><<<g2, 512, 0, stream>>>(hg, W2t, gate, b2, out, e0);
      else           gemm2_kernel<2, false><<<g2, 512, 0, stream>>>(hg, W2t, gate, b2, out, e0);
    } else {
      if (first)     gemm2_kernel<1, true ><<<g2, 512, 0, stream>>>(hg, W2t, gate, b2, out, e0);
      else           gemm2_kernel<1, false><<<g2, 512, 0, stream>>>(hg, W2t, gate, b2, out, e0);
    }
  }
}

// Round 6
// 695.625 us; speedup vs baseline: 1.0626x; 1.0135x over previous
//
#include <hip/hip_runtime.h>
#include <hip/hip_bf16.h>
#include <stdint.h>

// ---------------------------------------------------------------------------
// MoE dense:  B=4 T=2048 D=1024 H=2048 E=8   (fp32 in/out, bf16 MFMA compute)
// R12: (a) GEMM bodies software-pipelined: A-frag reads issued one MFMA-group
//      ahead (read-ahead ~2 groups = 128 cyc of independent MFMA issue to
//      hide LDS queue latency; liveness ~10 regs). R11 evidence: gemm1 at
//      56% of its LDS roofline (sum-model), gemm2 at 77% -> overlap, not
//      bandwidth, is the gap.
//      (b) aux fusion: cvt_x folded into gating (x read once, -1 dispatch);
//      W1/W2 transposes fused into one z-extended dispatch per group (-2).
//      Unchanged (proven): staging, T2 both-sides swizzle (conflicts=0),
//      XCD swizzle, 1 raw barrier/tile, vmcnt(0)-with-full-tile-lead,
//      setprio around MFMA stream, epilogues, ws layout.
// ws layout: gate@0 (1MB), xb@1 (16), W1t@17 (4G), W2t@17+4G (4G),
//            hg@17+8G (32G).  need = 17 + 40G MB.
// ---------------------------------------------------------------------------

typedef __bf16 bf16_t;
typedef bf16_t bf16x8 __attribute__((ext_vector_type(8)));
typedef bf16_t bf16x4 __attribute__((ext_vector_type(4)));
typedef float  f32x4  __attribute__((ext_vector_type(4)));

#define Ddim 1024
#define Hdim 2048
#define Edim 8
#define Mdim 8192

__device__ __forceinline__ void async16(const void* g, const void* l) {
  __builtin_amdgcn_global_load_lds(
      (const __attribute__((address_space(1))) void*)(uintptr_t)g,
      (__attribute__((address_space(3))) void*)(uint32_t)(uintptr_t)l,
      16, 0, 0);
}

#define MFMA(a, b, c) __builtin_amdgcn_mfma_f32_16x16x32_bf16((a), (b), (c), 0, 0, 0)

#define WAIT_VM0() do {                                    \
    asm volatile("s_waitcnt vmcnt(0)" ::: "memory");       \
    __builtin_amdgcn_sched_barrier(0);                     \
  } while (0)

// -------- gating + x->bf16 conversion fused: one wave per token -----------
__global__ void gating_cvt_kernel(const float* __restrict__ x,
                                  const float* __restrict__ Wg,
                                  const float* __restrict__ bg,
                                  float* __restrict__ gate,
                                  bf16_t* __restrict__ xb) {
  const int lane = threadIdx.x & 63;
  const int wid  = threadIdx.x >> 6;
  const int t    = blockIdx.x * 4 + wid;
  const float* xr = x + (size_t)t * Ddim;
  bf16_t* xbr = xb + (size_t)t * Ddim;
  float acc[8] = {0.f,0.f,0.f,0.f,0.f,0.f,0.f,0.f};
  for (int i = lane; i < Ddim; i += 64) {
    float xv = xr[i];
    xbr[i] = (bf16_t)xv;                       // fused cvt_x
    f32x4 a = *(const f32x4*)(Wg + (size_t)i * 8);
    f32x4 b = *(const f32x4*)(Wg + (size_t)i * 8 + 4);
    acc[0] += xv * a[0]; acc[1] += xv * a[1];
    acc[2] += xv * a[2]; acc[3] += xv * a[3];
    acc[4] += xv * b[0]; acc[5] += xv * b[1];
    acc[6] += xv * b[2]; acc[7] += xv * b[3];
  }
  #pragma unroll
  for (int e = 0; e < 8; ++e) {
    #pragma unroll
    for (int off = 32; off; off >>= 1)
      acc[e] += __shfl_xor(acc[e], off, 64);
  }
  if (lane == 0) {
    float l[8], mx = -1e30f;
    #pragma unroll
    for (int e = 0; e < 8; ++e) { l[e] = acc[e] + bg[e]; mx = fmaxf(mx, l[e]); }
    float s = 0.f;
    #pragma unroll
    for (int e = 0; e < 8; ++e) { l[e] = __expf(l[e] - mx); s += l[e]; }
    float inv = 1.f / s;
    #pragma unroll
    for (int e = 0; e < 8; ++e) gate[(size_t)t * 8 + e] = l[e] * inv;
  }
}

// ---- fused batched transpose: z<G -> W1[D,H]->W1t[H,D]; z>=G -> W2 -------
__global__ void transpose_both(const float* __restrict__ W1s,
                               const float* __restrict__ W2s,
                               bf16_t* __restrict__ W1t,
                               bf16_t* __restrict__ W2t) {
  __shared__ bf16_t tile[32][33];
  const int G = gridDim.y >> 1;
  const int z = blockIdx.y;
  const float* src; bf16_t* dst; int C, bx, by;
  if (z < G) {
    src = W1s + (size_t)z * Ddim * Hdim;
    dst = W1t + (size_t)z * Ddim * Hdim;
    C = Hdim; bx = blockIdx.x & 63; by = blockIdx.x >> 6;   // R=1024, C=2048
  } else {
    const int e = z - G;
    src = W2s + (size_t)e * Ddim * Hdim;
    dst = W2t + (size_t)e * Ddim * Hdim;
    C = Ddim; bx = blockIdx.x & 31; by = blockIdx.x >> 5;   // R=2048, C=1024
  }
  const int R = (z < G) ? Ddim : Hdim;
  const int r0 = by * 32, c0 = bx * 32;
  const int tr = threadIdx.x >> 3;
  const int tc = (threadIdx.x & 7) * 4;
  f32x4 v = *(const f32x4*)(src + (size_t)(r0 + tr) * C + c0 + tc);
  tile[tr][tc+0] = (bf16_t)v[0]; tile[tr][tc+1] = (bf16_t)v[1];
  tile[tr][tc+2] = (bf16_t)v[2]; tile[tr][tc+3] = (bf16_t)v[3];
  __syncthreads();
  bf16x4 o;
  o[0] = tile[tc+0][tr]; o[1] = tile[tc+1][tr];
  o[2] = tile[tc+2][tr]; o[3] = tile[tc+3][tr];
  *(bf16x4*)(dst + (size_t)(c0 + tr) * R + r0 + tc) = o;
}

// ---------------- GEMM1: hg[z] = gate_e * relu(xb @ W1t[z]^T + b1[e]) -----
// BM=256 BN=256 BK=64, 512 thr / 8 waves (2Mx4N, wave-tile 128x64).
// Per K-tile: stage 8; body = {8 B-reads; A-reads pipelined 1 group ahead,
// 8x(2 A-reads[i+1] -> 8 MFMA[i])}; vmcnt(0) full-lead; 1 raw barrier.
// grid (Hdim/256, Mdim/256, G); K = Ddim.
__launch_bounds__(512, 2)
__global__ void gemm1_kernel(const bf16_t* __restrict__ A,        // xb [M,D]
                             const bf16_t* __restrict__ W1tAll,   // [G,H,D]
                             const float*  __restrict__ gate,
                             const float*  __restrict__ b1,       // [E,H]
                             bf16_t* __restrict__ hgAll,          // [G,M,H]
                             int e0) {
  __shared__ alignas(16) bf16_t sA[2][256 * 64];   // 2 x 32KB
  __shared__ alignas(16) bf16_t sB[2][256 * 64];   // 2 x 32KB   (128KB total)

  const int tid  = threadIdx.x;
  const int lane = tid & 63;
  const int wid  = tid >> 6;
  const int wm   = wid >> 2, wn = wid & 3;     // 2M x 4N waves
  const int lrow = lane & 15, quad = lane >> 4;
  const int sb   = quad ^ (lrow & 7);          // swizzled 16B slot base

  const int z = blockIdx.z;
  const int e = e0 + z;
  const bf16_t* Bt = W1tAll + (size_t)z * Hdim * Ddim;
  bf16_t* hg = hgAll + (size_t)z * (size_t)Mdim * Hdim;
  const float* bias = b1 + (size_t)e * Hdim;

  // XCD swizzle within z-plane: 256 wgs -> 8 XCDs x 32
  const int bid = blockIdx.y * 8 + blockIdx.x;
  const int xcd = bid & 7, loc = bid >> 3;
  const int tileM = (xcd * 4 + (loc >> 3)) * 256;
  const int tileN = (loc & 7) * 256;

  // staging: thread -> (row = tid>>3, swizzled col16 = (tid&7) ^ (row&7))
  const int trow = tid >> 3;
  const int tsw  = ((tid & 7) ^ (trow & 7)) << 4;
  const int ldst = tid << 4;
  const size_t SA = (size_t)64 * Ddim * 2;     // 64-row byte stride

  const char* a0 = (const char*)(A  + (size_t)(tileM + trow) * Ddim) + tsw;
  const char* b0 = (const char*)(Bt + (size_t)(tileN + trow) * Ddim) + tsw;
  char* curA = (char*)&sA[0][0]; char* nxtA = (char*)&sA[1][0];
  char* curB = (char*)&sB[0][0]; char* nxtB = (char*)&sB[1][0];

  // prologue: fully stage K-tile 0, drain, publish
  async16(a0,          curA + 0 * 8192 + ldst);
  async16(a0 + SA,     curA + 1 * 8192 + ldst);
  async16(a0 + 2 * SA, curA + 2 * 8192 + ldst);
  async16(a0 + 3 * SA, curA + 3 * 8192 + ldst);
  async16(b0,          curB + 0 * 8192 + ldst);
  async16(b0 + SA,     curB + 1 * 8192 + ldst);
  async16(b0 + 2 * SA, curB + 2 * 8192 + ldst);
  async16(b0 + 3 * SA, curB + 3 * 8192 + ldst);
  a0 += 128; b0 += 128;
  WAIT_VM0();
  __builtin_amdgcn_s_barrier();

  f32x4 acc[8][4] = {};
  const int offA0 = (wm * 128 + lrow) * 128 + sb * 16;
  const int offA1 = (wm * 128 + lrow) * 128 + (sb ^ 4) * 16;
  const int offB0 = (wn * 64  + lrow) * 128 + sb * 16;
  const int offB1 = (wn * 64  + lrow) * 128 + (sb ^ 4) * 16;

  #pragma unroll 1
  for (int kk = 0; kk < Ddim / 64; ++kk) {
    const bool notlast = (kk + 1 < Ddim / 64);
    __builtin_amdgcn_sched_barrier(0);
    // stage K-tile kk+1 (issued at tile top -> full-tile lead on the drain)
    if (notlast) {
      async16(a0,          nxtA + 0 * 8192 + ldst);
      async16(a0 + SA,     nxtA + 1 * 8192 + ldst);
      async16(a0 + 2 * SA, nxtA + 2 * 8192 + ldst);
      async16(a0 + 3 * SA, nxtA + 3 * 8192 + ldst);
      async16(b0,          nxtB + 0 * 8192 + ldst);
      async16(b0 + SA,     nxtB + 1 * 8192 + ldst);
      async16(b0 + 2 * SA, nxtB + 2 * 8192 + ldst);
      async16(b0 + 3 * SA, nxtB + 3 * 8192 + ldst);
    }
    __builtin_amdgcn_sched_barrier(0);

    // body: 8 B-reads up front; A-reads pipelined one MFMA-group ahead
    bf16x8 bfr[4][2];
    #pragma unroll
    for (int j = 0; j < 4; ++j) {
      bfr[j][0] = *(const bf16x8*)(curB + offB0 + j * 2048);
      bfr[j][1] = *(const bf16x8*)(curB + offB1 + j * 2048);
    }
    bf16x8 ca0 = *(const bf16x8*)(curA + offA0);
    bf16x8 ca1 = *(const bf16x8*)(curA + offA1);
    __builtin_amdgcn_s_setprio(1);
    #pragma unroll
    for (int i = 0; i < 8; ++i) {
      bf16x8 na0, na1;
      if (i < 7) {
        na0 = *(const bf16x8*)(curA + offA0 + (i + 1) * 2048);
        na1 = *(const bf16x8*)(curA + offA1 + (i + 1) * 2048);
      }
      #pragma unroll
      for (int j = 0; j < 4; ++j) {
        acc[i][j] = MFMA(ca0, bfr[j][0], acc[i][j]);
        acc[i][j] = MFMA(ca1, bfr[j][1], acc[i][j]);
      }
      if (i < 7) { ca0 = na0; ca1 = na1; }
    }
    __builtin_amdgcn_s_setprio(0);

    WAIT_VM0();                          // loads had a full tile in flight
    __builtin_amdgcn_s_barrier();        // publish K-tile kk+1
    a0 += 128; b0 += 128;
    char* t;
    t = curA; curA = nxtA; nxtA = t;
    t = curB; curB = nxtB; nxtB = t;
  }

  // epilogue: bias + relu + gate, write bf16
  const int col0 = tileN + wn * 64 + lrow;
  float bcol[4];
  #pragma unroll
  for (int j = 0; j < 4; ++j) bcol[j] = bias[col0 + j * 16];
  #pragma unroll
  for (int i = 0; i < 8; ++i) {
    #pragma unroll
    for (int r = 0; r < 4; ++r) {
      const int row = tileM + wm * 128 + i * 16 + quad * 4 + r;
      const float g = gate[(size_t)row * 8 + e];
      #pragma unroll
      for (int j = 0; j < 4; ++j) {
        float v = acc[i][j][r] + bcol[j];
        v = fmaxf(v, 0.f) * g;
        hg[(size_t)row * Hdim + col0 + j * 16] = (bf16_t)v;
      }
    }
  }
}

// ---------------- GEMM2: out (+)= sum_g hg[g] @ W2t[g]^T + gate*b2 --------
// BM=256 BN=128 BK=64, 512 thr / 8 waves 4Mx2N (wave-tile 64x64).
// Body pipelined like gemm1.  K fused over group (NKT = G*32).
// grid (Ddim/128, Mdim/256) = 256.
template <int G, bool FIRST>
__launch_bounds__(512, 2)
__global__ void gemm2_kernel(const bf16_t* __restrict__ hgAll,    // [G,M,H]
                             const bf16_t* __restrict__ W2tAll,   // [G,D,H]
                             const float*  __restrict__ gate,
                             const float*  __restrict__ b2,       // [E,D]
                             float* __restrict__ out,             // [M,D]
                             int e0) {
  __shared__ alignas(16) bf16_t sA[2][256 * 64];   // 2 x 32KB
  __shared__ alignas(16) bf16_t sB[2][128 * 64];   // 2 x 16KB  (96KB total)

  const int tid  = threadIdx.x;
  const int lane = tid & 63;
  const int wid  = tid >> 6;
  const int wm   = wid >> 1, wn = wid & 1;     // 4M x 2N waves
  const int lrow = lane & 15, quad = lane >> 4;
  const int sb   = quad ^ (lrow & 7);

  const int bid = blockIdx.y * 8 + blockIdx.x;
  const int xcd = bid & 7, loc = bid >> 3;
  const int tileM = (xcd * 4 + (loc >> 3)) * 256;
  const int tileN = (loc & 7) * 128;

  const int trow = tid >> 3;
  const int tsw  = ((tid & 7) ^ (trow & 7)) << 4;
  const int ldst = tid << 4;
  const size_t S = (size_t)64 * Hdim * 2;          // 64-row byte stride

  const char* a0 = (const char*)(hgAll  + (size_t)(tileM + trow) * Hdim) + tsw;
  const char* b0 = (const char*)(W2tAll + (size_t)(tileN + trow) * Hdim) + tsw;
  char* curA = (char*)&sA[0][0]; char* nxtA = (char*)&sA[1][0];
  char* curB = (char*)&sB[0][0]; char* nxtB = (char*)&sB[1][0];

  // prologue: stage K-tile 0, drain, publish
  async16(a0,         curA + 0 * 8192 + ldst);
  async16(a0 + S,     curA + 1 * 8192 + ldst);
  async16(a0 + 2 * S, curA + 2 * 8192 + ldst);
  async16(a0 + 3 * S, curA + 3 * 8192 + ldst);
  async16(b0,         curB + 0 * 8192 + ldst);
  async16(b0 + S,     curB + 1 * 8192 + ldst);
  a0 += 128; b0 += 128;
  WAIT_VM0();
  __builtin_amdgcn_s_barrier();

  f32x4 acc[4][4] = {};
  const int offA0 = (wm * 64 + lrow) * 128 + sb * 16;
  const int offA1 = (wm * 64 + lrow) * 128 + (sb ^ 4) * 16;
  const int offB0 = (wn * 64 + lrow) * 128 + sb * 16;
  const int offB1 = (wn * 64 + lrow) * 128 + (sb ^ 4) * 16;

  const int NKT = G * (Hdim / 64);
  #pragma unroll 1
  for (int kk = 0; kk < NKT; ++kk) {
    const bool notlast = (kk + 1 < NKT);
    __builtin_amdgcn_sched_barrier(0);
    // expert-boundary rebase of staging pointers (targets kk+1)
    if (notlast && (((kk + 1) & 31) == 0)) {
      const int gn = (kk + 1) >> 5;
      a0 = (const char*)(hgAll  + (size_t)gn * Mdim * Hdim
                         + (size_t)(tileM + trow) * Hdim) + tsw;
      b0 = (const char*)(W2tAll + (size_t)gn * Ddim * Hdim
                         + (size_t)(tileN + trow) * Hdim) + tsw;
    }
    if (notlast) {
      async16(a0,         nxtA + 0 * 8192 + ldst);
      async16(a0 + S,     nxtA + 1 * 8192 + ldst);
      async16(a0 + 2 * S, nxtA + 2 * 8192 + ldst);
      async16(a0 + 3 * S, nxtA + 3 * 8192 + ldst);
      async16(b0,         nxtB + 0 * 8192 + ldst);
      async16(b0 + S,     nxtB + 1 * 8192 + ldst);
    }
    __builtin_amdgcn_sched_barrier(0);

    bf16x8 bfr[4][2];
    #pragma unroll
    for (int j = 0; j < 4; ++j) {
      bfr[j][0] = *(const bf16x8*)(curB + offB0 + j * 2048);
      bfr[j][1] = *(const bf16x8*)(curB + offB1 + j * 2048);
    }
    bf16x8 ca0 = *(const bf16x8*)(curA + offA0);
    bf16x8 ca1 = *(const bf16x8*)(curA + offA1);
    __builtin_amdgcn_s_setprio(1);
    #pragma unroll
    for (int i = 0; i < 4; ++i) {
      bf16x8 na0, na1;
      if (i < 3) {
        na0 = *(const bf16x8*)(curA + offA0 + (i + 1) * 2048);
        na1 = *(const bf16x8*)(curA + offA1 + (i + 1) * 2048);
      }
      #pragma unroll
      for (int j = 0; j < 4; ++j) {
        acc[i][j] = MFMA(ca0, bfr[j][0], acc[i][j]);
        acc[i][j] = MFMA(ca1, bfr[j][1], acc[i][j]);
      }
      if (i < 3) { ca0 = na0; ca1 = na1; }
    }
    __builtin_amdgcn_s_setprio(0);
    WAIT_VM0();
    __builtin_amdgcn_s_barrier();
    a0 += 128; b0 += 128;
    char* t;
    t = curA; curA = nxtA; nxtA = t;
    t = curB; curB = nxtB; nxtB = t;
  }

  // epilogue: add sum_g gate[row,e0+g]*b2[e0+g,col]
  const int col0 = tileN + wn * 64 + lrow;
  float b2c[4][G];
  #pragma unroll
  for (int j = 0; j < 4; ++j)
    #pragma unroll
    for (int g = 0; g < G; ++g)
      b2c[j][g] = b2[(size_t)(e0 + g) * Ddim + col0 + j * 16];

  #pragma unroll
  for (int i = 0; i < 4; ++i) {
    #pragma unroll
    for (int r = 0; r < 4; ++r) {
      const int row = tileM + wm * 64 + i * 16 + quad * 4 + r;
      const float* gr = gate + (size_t)row * 8 + e0;
      float gv[G];
      #pragma unroll
      for (int g = 0; g < G; ++g) gv[g] = gr[g];
      #pragma unroll
      for (int j = 0; j < 4; ++j) {
        float v = acc[i][j][r];
        #pragma unroll
        for (int g = 0; g < G; ++g) v += gv[g] * b2c[j][g];
        if (FIRST) out[(size_t)row * Ddim + col0 + j * 16] = v;
        else       out[(size_t)row * Ddim + col0 + j * 16] += v;
      }
    }
  }
}

extern "C" void kernel_launch(void* const* d_in, const int* in_sizes, int n_in,
                              void* d_out, int out_size, void* d_ws, size_t ws_size,
                              hipStream_t stream) {
  const float* x  = (const float*)d_in[0];
  const float* Wg = (const float*)d_in[1];
  const float* bg = (const float*)d_in[2];
  const float* W1 = (const float*)d_in[3];
  const float* b1 = (const float*)d_in[4];
  const float* W2 = (const float*)d_in[5];
  const float* b2 = (const float*)d_in[6];
  float* out = (float*)d_out;

  // ws-adaptive group size: need = 17 + 40G MB
  int G = 1;
  if      (ws_size >= (size_t)(17 + 40 * 8) << 20) G = 8;
  else if (ws_size >= (size_t)(17 + 40 * 4) << 20) G = 4;
  else if (ws_size >= (size_t)(17 + 40 * 2) << 20) G = 2;

  char* ws = (char*)d_ws;
  float*  gate = (float*)ws;                                     // 1 MB region
  bf16_t* xb   = (bf16_t*)(ws + (1u << 20));                     // 16 MB
  bf16_t* W1t  = (bf16_t*)(ws + (17u << 20));                    // 4G MB
  bf16_t* W2t  = (bf16_t*)(ws + ((size_t)(17 + 4 * G) << 20));   // 4G MB
  bf16_t* hg   = (bf16_t*)(ws + ((size_t)(17 + 8 * G) << 20));   // 32G MB

  gating_cvt_kernel<<<Mdim / 4, 256, 0, stream>>>(x, Wg, bg, gate, xb);

  const int nGroups = Edim / G;
  for (int gi = 0; gi < nGroups; ++gi) {
    const int e0 = gi * G;
    // fused W1 + W2 transpose for this group (z in [0,2G))
    transpose_both<<<dim3(2048, 2 * G), 256, 0, stream>>>(
        W1 + (size_t)e0 * Ddim * Hdim, W2 + (size_t)e0 * Hdim * Ddim, W1t, W2t);

    gemm1_kernel<<<dim3(Hdim / 256, Mdim / 256, G), 512, 0, stream>>>(
        xb, W1t, gate, b1, hg, e0);

    const dim3 g2(Ddim / 128, Mdim / 256);
    const bool first = (gi == 0);
    if (G == 8)      gemm2_kernel<8, true ><<<g2, 512, 0, stream>>>(hg, W2t, gate, b2, out, e0);
    else if (G == 4) {
      if (first)     gemm2_kernel<4, true ><<<g2, 512, 0, stream>>>(hg, W2t, gate, b2, out, e0);
      else           gemm2_kernel<4, false><<<g2, 512, 0, stream>>>(hg, W2t, gate, b2, out, e0);
    } else if (G == 2) {
      if (first)     gemm2_kernel<2, true ><<<g2, 512, 0, stream>>>(hg, W2t, gate, b2, out, e0);
      else           gemm2_kernel<2, false><<<g2, 512, 0, stream>>>(hg, W2t, gate, b2, out, e0);
    } else {
      if (first)     gemm2_kernel<1, true ><<<g2, 512, 0, stream>>>(hg, W2t, gate, b2, out, e0);
      else           gemm2_kernel<1, false><<<g2, 512, 0, stream>>>(hg, W2t, gate, b2, out, e0);
    }
  }
}